// Round 5
// baseline (198.791 us; speedup 1.0000x reference)
//
#include <hip/hip_runtime.h>

#define TC 128
#define KD 64
#define WLOG_MIN (-5.2983174f)   // ln(0.005)

typedef __attribute__((ext_vector_type(8))) short short8;
typedef __attribute__((ext_vector_type(4))) short short4_t;
typedef __attribute__((ext_vector_type(4))) float f32x4;

__device__ __forceinline__ unsigned short f2bf(float x) {
  union { float f; unsigned int u; } c; c.f = x;
  unsigned int u = c.u + 0x7fffu + ((c.u >> 16) & 1u);   // RNE
  return (unsigned short)(u >> 16);
}
__device__ __forceinline__ float bf2f(unsigned short x) {
  union { unsigned int u; float f; } c; c.u = ((unsigned int)x) << 16; return c.f;
}

// rd_s/ki_s swizzle: element (t,kd) stored at t*64 + (slot<<3 | kd&7),
// slot = (kd>>3) ^ (t&7) ^ ((t>>3)&7).  b128 granule-q reads use
// slot = q ^ (t&7) ^ ((t>>3)&7).  vT/kiT swizzle: slot = g ^ (row&7).

// ---------------------------------------------------------------------------
// K1: per-(b,h,chunk), 512 threads / 8 waves, 16-timestep segment per wave.
// This round: asm "+v" pins after the load block — round 4's issue-early
// loads were re-sunk by the compiler (VGPR stayed 52); the pins force the
// 64 loads to stay issued-in-bulk (one latency window, all in flight)
// instead of 16 exposed per-iteration stalls in pass 2.
// ---------------------------------------------------------------------------
__global__ __launch_bounds__(512, 4)
void rwkv_intra_mfma(const float* __restrict__ rr, const float* __restrict__ kk_,
                     const float* __restrict__ vv, const float* __restrict__ ww,
                     const float* __restrict__ uu, float* __restrict__ out,
                     unsigned short* __restrict__ wkv_u16, float* __restrict__ wse_ws,
                     unsigned short* __restrict__ rw_u16, unsigned short* __restrict__ diag_u16,
                     int H, int N) {
  __shared__ alignas(16) unsigned short rd_s[TC * KD];
  __shared__ alignas(16) unsigned short ki_s[TC * KD];
  __shared__ alignas(16) unsigned short vT_s[KD * TC];
  __shared__ alignas(16) unsigned short kiT_s[KD * TC];
  __shared__ alignas(16) unsigned char su_raw[10240];  // union: segtot f32[8][64] | Ast u16[8][640]
  float* segtot = (float*)su_raw;
  unsigned short* Ast = (unsigned short*)su_raw;

  const int bid = blockIdx.x;
  const int n = bid % N, bh = bid / N, h = bh % H;
  const size_t base = ((size_t)bh * N + n) * (TC * KD);
  const float *rg = rr + base, *kg = kk_ + base, *vg = vv + base, *wg = ww + base;
  unsigned short* diagg = diag_u16 + (size_t)bid * TC;

  const int tid = threadIdx.x;
  const int lk = tid & 63;    // k-column during staging (= lane)
  const int wv = tid >> 6;    // wave id = 16-row t-segment (0..7)

  // ---- issue-early: ALL global loads for this thread, before any compute ----
  float wl[16];
  #pragma unroll
  for (int tt = 0; tt < 16; ++tt)
    wl[tt] = wg[(wv * 16 + tt) * KD + lk];
  float rv_[16], kv_[16], vv_[16];
  #pragma unroll
  for (int tt = 0; tt < 16; ++tt) {
    const int t = wv * 16 + tt;
    rv_[tt] = rg[t * KD + lk];
    kv_[tt] = kg[t * KD + lk];
    vv_[tt] = vg[t * KD + lk];
  }
  float uk = uu[h * KD + lk];
  // Pin: asm consumes every loaded value -> loads CANNOT be sunk below this
  // point. One bulk waitcnt here (64 loads in flight concurrently) replaces
  // 16 exposed stalls inside pass 2. Costs ~64 VGPR (still <=128 -> 2 blk/CU).
  #pragma unroll
  for (int tt = 0; tt < 16; ++tt)
    asm volatile("" : "+v"(wl[tt]), "+v"(rv_[tt]), "+v"(kv_[tt]), "+v"(vv_[tt]));
  asm volatile("" : "+v"(uk));

  // ---- pass 1: w clamp + segment totals ----
  {
    float c = 0.f;
    #pragma unroll
    for (int tt = 0; tt < 16; ++tt) {
      wl[tt] = fmaxf(wl[tt], WLOG_MIN);
      c += wl[tt];
    }
    segtot[wv * 64 + lk] = c;
  }
  __syncthreads();
  float segofs = 0.f, myoff = 0.f, wsum = 0.f;
  #pragma unroll
  for (int i = 0; i < 8; ++i) {
    const float si = segtot[i * 64 + lk];
    if (i < wv) segofs += si;
    if (i < 4) myoff += si;     // cum at t = Tc/2
    wsum += si;
  }
  const float wsoff_own = __expf(wsum - myoff);   // kept in reg (segtot gets clobbered by Ast)
  if (wv == 0) wse_ws[((size_t)bh * N + n) * KD + lk] = __expf(wsum);
  const float eoff = __expf(myoff);

  // ---- pass 2: staging (pure compute + LDS/global stores) ----
  {
    float c = segofs;
    unsigned short* rwg = rw_u16 + base;
    short8 vb8, kib8;
    float darr[8];
    #pragma unroll
    for (int tt = 0; tt < 16; ++tt) {
      const int t = wv * 16 + tt;
      const float rv = rv_[tt], kv = kv_[tt], vvv = vv_[tt];
      const int slot = (lk >> 3) ^ (t & 7) ^ ((t >> 3) & 7);
      const int nat = t * KD + (slot << 3) + (lk & 7);
      float e1 = __expf(c - myoff);
      rd_s[nat] = f2bf(rv * e1);
      rwg[t * KD + lk] = f2bf(rv * e1 * eoff);  // r * exp(cum) for scan_inter
      const unsigned short kiv = f2bf(kv * __expf(myoff - c - wl[tt]));
      ki_s[nat] = kiv;
      kib8[tt & 7] = (short)kiv;
      vb8[tt & 7] = (short)f2bf(vvv);
      darr[tt & 7] = rv * uk * kv;
      c += wl[tt];
      if ((tt & 7) == 7) {
        const int g = t >> 3;
        *(short8*)&vT_s[lk * TC + ((g ^ (lk & 7)) << 3)] = vb8;
        *(short8*)&kiT_s[lk * TC + ((g ^ (lk & 7)) << 3)] = kib8;
        // batched butterfly: 8 independent reductions
        #pragma unroll
        for (int o = 32; o > 0; o >>= 1)
          #pragma unroll
          for (int q = 0; q < 8; ++q) darr[q] += __shfl_xor(darr[q], o, 64);
        if (lk == 0) {
          short8 dpk;
          #pragma unroll
          for (int q = 0; q < 8; ++q) dpk[q] = (short)f2bf(darr[q]);
          *(short8*)&diagg[g * 8] = dpk;
        }
      }
    }
  }
  __syncthreads();

  const int lane = tid & 63, quad = lane >> 4, l16 = lane & 15;

  // ---- wkv = (ki * w_inter)^T @ v -> bf16 ws (A-frags b128 from kiT) ----
  {
    const int kt = wv >> 1;             // kd-tile 0..3
    const int nb = (wv & 1) * 2;        // vd-tile base: {0,1} or {2,3}
    f32x4 acc[2] = {{0,0,0,0},{0,0,0,0}};
    const int row = kt * 16 + l16;      // kd row of ki^T
    #pragma unroll
    for (int ks = 0; ks < 4; ++ks) {
      short8 a = *(const short8*)&kiT_s[row * TC + (((ks * 4 + quad) ^ (row & 7)) << 3)];
      #pragma unroll
      for (int nn = 0; nn < 2; ++nn) {
        const int vd = (nb + nn) * 16 + l16;
        short8 b = *(const short8*)&vT_s[vd * TC + (((ks * 4 + quad) ^ (vd & 7)) << 3)];
        acc[nn] = __builtin_amdgcn_mfma_f32_16x16x32_bf16(a, b, acc[nn], 0, 0, 0);
      }
    }
    float wso[4];
    #pragma unroll
    for (int reg = 0; reg < 4; ++reg) wso[reg] = __shfl(wsoff_own, kt * 16 + quad * 4 + reg, 64);
    unsigned short* wkvg = wkv_u16 + ((size_t)bh * N + n) * (KD * KD);
    #pragma unroll
    for (int nn = 0; nn < 2; ++nn)
      #pragma unroll
      for (int reg = 0; reg < 4; ++reg)
        wkvg[(kt * 16 + quad * 4 + reg) * KD + (nb + nn) * 16 + l16] = f2bf(acc[nn][reg] * wso[reg]);
  }

  // ---- fused A^T tiles + out = A@v (one ib per wave, no block sync) ----
  {
    const int ib = wv;
    const int i0 = ib * 16;
    const int irow = i0 + l16;
    const int rsw = (irow & 7) ^ ((irow >> 3) & 7);
    short8 b0 = *(const short8*)&rd_s[irow * KD + ((quad ^ rsw) << 3)];
    short8 b1 = *(const short8*)&rd_s[irow * KD + (((4 + quad) ^ rsw) << 3)];
    const float diag_i = bf2f(diagg[irow]);
    f32x4 oacc[4] = {{0,0,0,0},{0,0,0,0},{0,0,0,0},{0,0,0,0}};
    const int npairs = (ib + 2) >> 1;
    unsigned short* astw = Ast + wv * 640;
    for (int jp = 0; jp < npairs; ++jp) {
      #pragma unroll
      for (int jj = 0; jj < 2; ++jj) {
        const int j = jp * 2 + jj;
        short4_t pk;
        if (j <= ib) {
          const int jrow = j * 16 + l16;
          const int jsw = (jrow & 7) ^ ((jrow >> 3) & 7);
          short8 a0 = *(const short8*)&ki_s[jrow * KD + ((quad ^ jsw) << 3)];
          short8 a1 = *(const short8*)&ki_s[jrow * KD + (((4 + quad) ^ jsw) << 3)];
          f32x4 at = {0, 0, 0, 0};
          at = __builtin_amdgcn_mfma_f32_16x16x32_bf16(a0, b0, at, 0, 0, 0);
          at = __builtin_amdgcn_mfma_f32_16x16x32_bf16(a1, b1, at, 0, 0, 0);
          #pragma unroll
          for (int reg = 0; reg < 4; ++reg) {
            const int je = j * 16 + quad * 4 + reg;
            float val = at[reg];
            if (j == ib) val = (je < irow) ? val : ((je == irow) ? diag_i : 0.f);
            pk[reg] = (short)f2bf(val);
          }
        } else {
          pk = (short4_t)0;  // guard half for even ib
        }
        *(short4_t*)&astw[l16 * 40 + jj * 16 + quad * 4] = pk;
      }
      short8 af = *(const short8*)&astw[l16 * 40 + quad * 8];
      #pragma unroll
      for (int nn = 0; nn < 4; ++nn) {
        const int vd = nn * 16 + l16;
        short8 bv = *(const short8*)&vT_s[vd * TC + (((jp * 4 + quad) ^ (vd & 7)) << 3)];
        oacc[nn] = __builtin_amdgcn_mfma_f32_16x16x32_bf16(af, bv, oacc[nn], 0, 0, 0);
      }
    }
    float* og = out + base;
    #pragma unroll
    for (int nn = 0; nn < 4; ++nn)
      #pragma unroll
      for (int reg = 0; reg < 4; ++reg)
        og[(i0 + quad * 4 + reg) * KD + nn * 16 + l16] = oacc[nn][reg];
  }
}

// ---------------------------------------------------------------------------
// K2 (fused scan+apply, fully parallel): block = (bh, n), BH*N = 1024 blocks.
// Each block recomputes S_n itself by scanning wkv[0..n-1] (L2/L3-hot: wkv
// is only 8.4 MB total). Then out += rw @ S_n with the accumulator repacked
// through a 17 KB LDS half-tile so the global RMW is float4 both ways.
// LDS 25,600 B -> 6 blocks/CU (24 waves/CU). (unchanged)
// ---------------------------------------------------------------------------
__global__ __launch_bounds__(256, 6)
void rwkv_scan_apply(const unsigned short* __restrict__ wkv_u16,
                     const float* __restrict__ wse_ws,
                     const float* __restrict__ st_in,
                     const unsigned short* __restrict__ rw_u16,
                     float* __restrict__ out, float* __restrict__ final_out, int N) {
  __shared__ alignas(16) unsigned short sT[KD * KD];    // 8 KB: S_n^T swizzled bf16
  __shared__ alignas(16) float obuf[64 * 68];           // 17,408 B: half-tile f32, stride 68

  const int bid = blockIdx.x;
  const int n = bid % N, bh = bid / N;
  const int tid = threadIdx.x;

  // ---- per-thread prefix scan: thread owns (kd = tid>>2, vd = v0..v0+15) ----
  const int kd = tid >> 2, v0 = (tid & 3) * 16;
  const size_t sbase = (size_t)bh * (KD * KD);
  float s[16];
  #pragma unroll
  for (int i = 0; i < 16; i += 4)
    *(f32x4*)&s[i] = *(const f32x4*)&st_in[sbase + kd * KD + v0 + i];

  const float* wseb = wse_ws + (size_t)bh * N * KD + kd;
  const unsigned short* wkvb = wkv_u16 + (size_t)bh * N * (KD * KD) + kd * KD + v0;

  {
    float e_c = 0.f; short8 x0_c = {0}, x1_c = {0};
    if (n > 0) {
      e_c = wseb[0];
      x0_c = *(const short8*)&wkvb[0];
      x1_c = *(const short8*)&wkvb[8];
    }
    for (int j = 0; j < n; ++j) {
      const float e = e_c; const short8 x0 = x0_c, x1 = x1_c;
      if (j + 1 < n) {
        e_c = wseb[(size_t)(j + 1) * KD];
        x0_c = *(const short8*)&wkvb[(size_t)(j + 1) * (KD * KD)];
        x1_c = *(const short8*)&wkvb[(size_t)(j + 1) * (KD * KD) + 8];
      }
      #pragma unroll
      for (int i = 0; i < 8; ++i) {
        s[i]     = s[i]     * e + bf2f((unsigned short)x0[i]);
        s[i + 8] = s[i + 8] * e + bf2f((unsigned short)x1[i]);
      }
    }
  }

  // ---- stage S_n^T into LDS (transpose + swizzle, from registers) ----
  {
    const int g = kd >> 3, k7 = kd & 7;
    #pragma unroll
    for (int i = 0; i < 16; ++i) {
      const int vd = v0 + i;
      sT[vd * KD + (((g ^ (vd & 7)) << 3) | k7)] = f2bf(s[i]);
    }
  }

  // ---- final state: only the n == N-1 blocks do one more step + write ----
  if (n == N - 1) {
    const float e = wseb[(size_t)(N - 1) * KD];
    const short8 x0 = *(const short8*)&wkvb[(size_t)(N - 1) * (KD * KD)];
    const short8 x1 = *(const short8*)&wkvb[(size_t)(N - 1) * (KD * KD) + 8];
    #pragma unroll
    for (int i = 0; i < 8; ++i) {
      s[i]     = s[i]     * e + bf2f((unsigned short)x0[i]);
      s[i + 8] = s[i + 8] * e + bf2f((unsigned short)x1[i]);
    }
    #pragma unroll
    for (int i = 0; i < 16; i += 4)
      *(f32x4*)&final_out[sbase + kd * KD + v0 + i] = *(const f32x4*)&s[i];
  }
  __syncthreads();

  // ---- out += rw @ S_n, epilogue via LDS half-tile for float4 RMW ----
  const int lane = tid & 63, wv = tid >> 6, quad = lane >> 4, l16 = lane & 15;
  const unsigned short* rwg = rw_u16 + ((size_t)bh * N + n) * (TC * KD);
  float* og = out + ((size_t)bh * N + n) * (TC * KD);
  #pragma unroll
  for (int half = 0; half < 2; ++half) {
    const int mt = wv + half * 4;
    const int trow = mt * 16 + l16;
    short8 a0 = *(const short8*)&rwg[trow * KD + quad * 8];
    short8 a1 = *(const short8*)&rwg[trow * KD + 32 + quad * 8];
    const int lr0 = (mt - half * 4) * 16 + quad * 4;   // local row base in obuf
    #pragma unroll
    for (int nn = 0; nn < 4; ++nn) {
      const int vd = nn * 16 + l16;
      short8 b0 = *(const short8*)&sT[vd * KD + ((quad ^ (vd & 7)) << 3)];
      short8 b1 = *(const short8*)&sT[vd * KD + (((4 + quad) ^ (vd & 7)) << 3)];
      f32x4 acc = {0, 0, 0, 0};
      acc = __builtin_amdgcn_mfma_f32_16x16x32_bf16(a0, b0, acc, 0, 0, 0);
      acc = __builtin_amdgcn_mfma_f32_16x16x32_bf16(a1, b1, acc, 0, 0, 0);
      #pragma unroll
      for (int reg = 0; reg < 4; ++reg)
        obuf[(lr0 + reg) * 68 + nn * 16 + l16] = acc[reg];
    }
    __syncthreads();
    // float4 RMW of 64 global rows (16 KB): 4 float4s per thread,
    // 1 KB contiguous per wave per instruction.
    {
      float* ogh = og + half * 64 * KD;
      #pragma unroll
      for (int i = 0; i < 4; ++i) {
        const int f = tid + i * 256;            // float4 index 0..1023
        const int row = f >> 4, c4 = (f & 15) * 4;
        f32x4 l = *(const f32x4*)&obuf[row * 68 + c4];
        f32x4 gv = *(const f32x4*)&ogh[row * KD + c4];
        gv += l;
        *(f32x4*)&ogh[row * KD + c4] = gv;
      }
    }
    __syncthreads();
  }
}

// ---------------------------------------------------------------------------
// Workspace (~24.75 MB): [wkv u16: BH*N*K*K][wse f32: BH*N*K]
//                        [rw u16: BH*T*K][diag u16: BH*N*TC]
// ---------------------------------------------------------------------------
extern "C" void kernel_launch(void* const* d_in, const int* in_sizes, int n_in,
                              void* d_out, int out_size, void* d_ws, size_t ws_size,
                              hipStream_t stream) {
  const float* r = (const float*)d_in[0];
  const float* k = (const float*)d_in[1];
  const float* v = (const float*)d_in[2];
  const float* w = (const float*)d_in[3];
  const float* u = (const float*)d_in[4];
  const float* st0 = (const float*)d_in[5];
  float* out = (float*)d_out;

  const int BH = in_sizes[5] / (KD * KD);  // 64
  const int H = in_sizes[4] / KD;          // 16
  const int T = in_sizes[0] / (BH * KD);   // 2048
  const int N = T / TC;                    // 16

  unsigned short* wkv_u16 = (unsigned short*)d_ws;
  float* wse_ws = (float*)(wkv_u16 + (size_t)BH * N * KD * KD);
  unsigned short* rw_u16 = (unsigned short*)(wse_ws + (size_t)BH * N * KD);
  unsigned short* diag_u16 = rw_u16 + (size_t)BH * T * KD;
  float* final_out = out + (size_t)in_sizes[0];

  rwkv_intra_mfma<<<BH * N, 512, 0, stream>>>(r, k, v, w, u, out, wkv_u16, wse_ws,
                                              rw_u16, diag_u16, H, N);
  rwkv_scan_apply<<<BH * N, 256, 0, stream>>>(wkv_u16, wse_ws, st0, rw_u16,
                                              out, final_out, N);
}

// Round 6
// 198.127 us; speedup vs baseline: 1.0034x; 1.0034x over previous
//
#include <hip/hip_runtime.h>

#define TC 128
#define KD 64
#define WLOG_MIN (-5.2983174f)   // ln(0.005)

typedef __attribute__((ext_vector_type(8))) short short8;
typedef __attribute__((ext_vector_type(4))) short short4_t;
typedef __attribute__((ext_vector_type(4))) float f32x4;

__device__ __forceinline__ unsigned short f2bf(float x) {
  union { float f; unsigned int u; } c; c.f = x;
  unsigned int u = c.u + 0x7fffu + ((c.u >> 16) & 1u);   // RNE
  return (unsigned short)(u >> 16);
}
__device__ __forceinline__ float bf2f(unsigned short x) {
  union { unsigned int u; float f; } c; c.u = ((unsigned int)x) << 16; return c.f;
}

// rd_s/ki_s swizzle: element (t,kd) stored at t*64 + (slot<<3 | kd&7),
// slot = (kd>>3) ^ (t&7) ^ ((t>>3)&7).  b128 granule-q reads use
// slot = q ^ (t&7) ^ ((t>>3)&7).  vT/kiT swizzle: slot = g ^ (row&7).

// asm global_load: row stride is 256 B, 16 rows span 0..3840 B -> one base
// pointer per array + 13-bit literal offsets. asm volatile => the compiler
// cannot sink/split the load block (rounds 4/5: source-level hoists and
// empty-asm pins were both defeated; VGPR stayed 52, ~1 load in flight,
// MLP-limited to the measured ~2 TB/s).
#define GLD(dst, ptr, OFF) \
  asm volatile("global_load_dword %0, %1, off offset:" #OFF : "=v"(dst) : "v"(ptr))
#define GLD16(arr, ptr)                                                        \
  GLD(arr[0], ptr, 0);    GLD(arr[1], ptr, 256);  GLD(arr[2], ptr, 512);       \
  GLD(arr[3], ptr, 768);  GLD(arr[4], ptr, 1024); GLD(arr[5], ptr, 1280);      \
  GLD(arr[6], ptr, 1536); GLD(arr[7], ptr, 1792); GLD(arr[8], ptr, 2048);      \
  GLD(arr[9], ptr, 2304); GLD(arr[10], ptr, 2560); GLD(arr[11], ptr, 2816);    \
  GLD(arr[12], ptr, 3072); GLD(arr[13], ptr, 3328); GLD(arr[14], ptr, 3584);   \
  GLD(arr[15], ptr, 3840)
#define PIN16(a)                                                               \
  asm volatile("" : "+v"(a[0]), "+v"(a[1]), "+v"(a[2]), "+v"(a[3]),            \
                    "+v"(a[4]), "+v"(a[5]), "+v"(a[6]), "+v"(a[7]),            \
                    "+v"(a[8]), "+v"(a[9]), "+v"(a[10]), "+v"(a[11]),          \
                    "+v"(a[12]), "+v"(a[13]), "+v"(a[14]), "+v"(a[15]))

// ---------------------------------------------------------------------------
// K1: per-(b,h,chunk), 512 threads / 8 waves, 16-timestep segment per wave.
// This round: all 64 w/r/k/v loads issued as one asm-volatile block at entry
// (48-64 outstanding per wave vs ~1 before). w gated by s_waitcnt vmcnt(48)
// with dataflow ties; r/k/v gated by the pass-1 barrier's vmcnt(0) drain +
// post-barrier dataflow pins. LDS 75,776 B -> 2 blocks/CU, 16 waves/CU.
// ---------------------------------------------------------------------------
__global__ __launch_bounds__(512, 4)
void rwkv_intra_mfma(const float* __restrict__ rr, const float* __restrict__ kk_,
                     const float* __restrict__ vv, const float* __restrict__ ww,
                     const float* __restrict__ uu, float* __restrict__ out,
                     unsigned short* __restrict__ wkv_u16, float* __restrict__ wse_ws,
                     unsigned short* __restrict__ rw_u16, unsigned short* __restrict__ diag_u16,
                     int H, int N) {
  __shared__ alignas(16) unsigned short rd_s[TC * KD];
  __shared__ alignas(16) unsigned short ki_s[TC * KD];
  __shared__ alignas(16) unsigned short vT_s[KD * TC];
  __shared__ alignas(16) unsigned short kiT_s[KD * TC];
  __shared__ alignas(16) unsigned char su_raw[10240];  // union: segtot f32[8][64] | Ast u16[8][640]
  float* segtot = (float*)su_raw;
  unsigned short* Ast = (unsigned short*)su_raw;

  const int bid = blockIdx.x;
  const int n = bid % N, bh = bid / N, h = bh % H;
  const size_t base = ((size_t)bh * N + n) * (TC * KD);
  const float *rg = rr + base, *kg = kk_ + base, *vg = vv + base, *wg = ww + base;
  unsigned short* diagg = diag_u16 + (size_t)bid * TC;

  const int tid = threadIdx.x;
  const int lk = tid & 63;    // k-column during staging (= lane)
  const int wv = tid >> 6;    // wave id = 16-row t-segment (0..7)

  // ---- asm bulk-issue: w first (needed in pass 1), then r/k/v ----
  const float* wp = wg + (wv * 16) * KD + lk;
  const float* rp = rg + (wv * 16) * KD + lk;
  const float* kp = kg + (wv * 16) * KD + lk;
  const float* vp = vg + (wv * 16) * KD + lk;
  float wl[16], rv_[16], kv_[16], vv_[16];
  GLD16(wl, wp);
  GLD16(rv_, rp);
  GLD16(kv_, kp);
  GLD16(vv_, vp);
  const float uk = uu[h * KD + lk];

  // Wait for the 16 w loads only (48 r/k/v remain in flight through pass 1).
  // "+v" ties make every wl use data-depend on this waitcnt; sched_barrier
  // stops the machine scheduler from hoisting anything above it (rule #18).
  asm volatile("s_waitcnt vmcnt(48)"
               : "+v"(wl[0]), "+v"(wl[1]), "+v"(wl[2]), "+v"(wl[3]),
                 "+v"(wl[4]), "+v"(wl[5]), "+v"(wl[6]), "+v"(wl[7]),
                 "+v"(wl[8]), "+v"(wl[9]), "+v"(wl[10]), "+v"(wl[11]),
                 "+v"(wl[12]), "+v"(wl[13]), "+v"(wl[14]), "+v"(wl[15]));
  __builtin_amdgcn_sched_barrier(0);

  // ---- pass 1: w clamp + segment totals ----
  {
    float c = 0.f;
    #pragma unroll
    for (int tt = 0; tt < 16; ++tt) {
      wl[tt] = fmaxf(wl[tt], WLOG_MIN);
      c += wl[tt];
    }
    segtot[wv * 64 + lk] = c;
  }
  __syncthreads();   // emits s_waitcnt vmcnt(0): r/k/v loads complete here
  // Post-barrier dataflow pins: no rv_/kv_/vv_ use can hoist above the drain.
  PIN16(rv_); PIN16(kv_); PIN16(vv_);
  __builtin_amdgcn_sched_barrier(0);

  float segofs = 0.f, myoff = 0.f, wsum = 0.f;
  #pragma unroll
  for (int i = 0; i < 8; ++i) {
    const float si = segtot[i * 64 + lk];
    if (i < wv) segofs += si;
    if (i < 4) myoff += si;     // cum at t = Tc/2
    wsum += si;
  }
  const float wsoff_own = __expf(wsum - myoff);   // kept in reg (segtot gets clobbered by Ast)
  if (wv == 0) wse_ws[((size_t)bh * N + n) * KD + lk] = __expf(wsum);
  const float eoff = __expf(myoff);

  // ---- pass 2: staging (pure compute + LDS/global stores, zero load stall) ----
  {
    float c = segofs;
    unsigned short* rwg = rw_u16 + base;
    short8 vb8, kib8;
    float darr[8];
    #pragma unroll
    for (int tt = 0; tt < 16; ++tt) {
      const int t = wv * 16 + tt;
      const float rv = rv_[tt], kv = kv_[tt], vvv = vv_[tt];
      const int slot = (lk >> 3) ^ (t & 7) ^ ((t >> 3) & 7);
      const int nat = t * KD + (slot << 3) + (lk & 7);
      float e1 = __expf(c - myoff);
      rd_s[nat] = f2bf(rv * e1);
      rwg[t * KD + lk] = f2bf(rv * e1 * eoff);  // r * exp(cum) for scan_inter
      const unsigned short kiv = f2bf(kv * __expf(myoff - c - wl[tt]));
      ki_s[nat] = kiv;
      kib8[tt & 7] = (short)kiv;
      vb8[tt & 7] = (short)f2bf(vvv);
      darr[tt & 7] = rv * uk * kv;
      c += wl[tt];
      if ((tt & 7) == 7) {
        const int g = t >> 3;
        *(short8*)&vT_s[lk * TC + ((g ^ (lk & 7)) << 3)] = vb8;
        *(short8*)&kiT_s[lk * TC + ((g ^ (lk & 7)) << 3)] = kib8;
        // batched butterfly: 8 independent reductions
        #pragma unroll
        for (int o = 32; o > 0; o >>= 1)
          #pragma unroll
          for (int q = 0; q < 8; ++q) darr[q] += __shfl_xor(darr[q], o, 64);
        if (lk == 0) {
          short8 dpk;
          #pragma unroll
          for (int q = 0; q < 8; ++q) dpk[q] = (short)f2bf(darr[q]);
          *(short8*)&diagg[g * 8] = dpk;
        }
      }
    }
  }
  __syncthreads();

  const int lane = tid & 63, quad = lane >> 4, l16 = lane & 15;

  // ---- wkv = (ki * w_inter)^T @ v -> bf16 ws (A-frags b128 from kiT) ----
  {
    const int kt = wv >> 1;             // kd-tile 0..3
    const int nb = (wv & 1) * 2;        // vd-tile base: {0,1} or {2,3}
    f32x4 acc[2] = {{0,0,0,0},{0,0,0,0}};
    const int row = kt * 16 + l16;      // kd row of ki^T
    #pragma unroll
    for (int ks = 0; ks < 4; ++ks) {
      short8 a = *(const short8*)&kiT_s[row * TC + (((ks * 4 + quad) ^ (row & 7)) << 3)];
      #pragma unroll
      for (int nn = 0; nn < 2; ++nn) {
        const int vd = (nb + nn) * 16 + l16;
        short8 b = *(const short8*)&vT_s[vd * TC + (((ks * 4 + quad) ^ (vd & 7)) << 3)];
        acc[nn] = __builtin_amdgcn_mfma_f32_16x16x32_bf16(a, b, acc[nn], 0, 0, 0);
      }
    }
    float wso[4];
    #pragma unroll
    for (int reg = 0; reg < 4; ++reg) wso[reg] = __shfl(wsoff_own, kt * 16 + quad * 4 + reg, 64);
    unsigned short* wkvg = wkv_u16 + ((size_t)bh * N + n) * (KD * KD);
    #pragma unroll
    for (int nn = 0; nn < 2; ++nn)
      #pragma unroll
      for (int reg = 0; reg < 4; ++reg)
        wkvg[(kt * 16 + quad * 4 + reg) * KD + (nb + nn) * 16 + l16] = f2bf(acc[nn][reg] * wso[reg]);
  }

  // ---- fused A^T tiles + out = A@v (one ib per wave, no block sync) ----
  {
    const int ib = wv;
    const int i0 = ib * 16;
    const int irow = i0 + l16;
    const int rsw = (irow & 7) ^ ((irow >> 3) & 7);
    short8 b0 = *(const short8*)&rd_s[irow * KD + ((quad ^ rsw) << 3)];
    short8 b1 = *(const short8*)&rd_s[irow * KD + (((4 + quad) ^ rsw) << 3)];
    const float diag_i = bf2f(diagg[irow]);
    f32x4 oacc[4] = {{0,0,0,0},{0,0,0,0},{0,0,0,0},{0,0,0,0}};
    const int npairs = (ib + 2) >> 1;
    unsigned short* astw = Ast + wv * 640;
    for (int jp = 0; jp < npairs; ++jp) {
      #pragma unroll
      for (int jj = 0; jj < 2; ++jj) {
        const int j = jp * 2 + jj;
        short4_t pk;
        if (j <= ib) {
          const int jrow = j * 16 + l16;
          const int jsw = (jrow & 7) ^ ((jrow >> 3) & 7);
          short8 a0 = *(const short8*)&ki_s[jrow * KD + ((quad ^ jsw) << 3)];
          short8 a1 = *(const short8*)&ki_s[jrow * KD + (((4 + quad) ^ jsw) << 3)];
          f32x4 at = {0, 0, 0, 0};
          at = __builtin_amdgcn_mfma_f32_16x16x32_bf16(a0, b0, at, 0, 0, 0);
          at = __builtin_amdgcn_mfma_f32_16x16x32_bf16(a1, b1, at, 0, 0, 0);
          #pragma unroll
          for (int reg = 0; reg < 4; ++reg) {
            const int je = j * 16 + quad * 4 + reg;
            float val = at[reg];
            if (j == ib) val = (je < irow) ? val : ((je == irow) ? diag_i : 0.f);
            pk[reg] = (short)f2bf(val);
          }
        } else {
          pk = (short4_t)0;  // guard half for even ib
        }
        *(short4_t*)&astw[l16 * 40 + jj * 16 + quad * 4] = pk;
      }
      short8 af = *(const short8*)&astw[l16 * 40 + quad * 8];
      #pragma unroll
      for (int nn = 0; nn < 4; ++nn) {
        const int vd = nn * 16 + l16;
        short8 bv = *(const short8*)&vT_s[vd * TC + (((jp * 4 + quad) ^ (vd & 7)) << 3)];
        oacc[nn] = __builtin_amdgcn_mfma_f32_16x16x32_bf16(af, bv, oacc[nn], 0, 0, 0);
      }
    }
    float* og = out + base;
    #pragma unroll
    for (int nn = 0; nn < 4; ++nn)
      #pragma unroll
      for (int reg = 0; reg < 4; ++reg)
        og[(i0 + quad * 4 + reg) * KD + nn * 16 + l16] = oacc[nn][reg];
  }
}

// ---------------------------------------------------------------------------
// K2 (fused scan+apply, fully parallel): block = (bh, n), BH*N = 1024 blocks.
// Each block recomputes S_n itself by scanning wkv[0..n-1] (L2/L3-hot: wkv
// is only 8.4 MB total). Then out += rw @ S_n with the accumulator repacked
// through a 17 KB LDS half-tile so the global RMW is float4 both ways.
// LDS 25,600 B -> 6 blocks/CU (24 waves/CU). (unchanged)
// ---------------------------------------------------------------------------
__global__ __launch_bounds__(256, 6)
void rwkv_scan_apply(const unsigned short* __restrict__ wkv_u16,
                     const float* __restrict__ wse_ws,
                     const float* __restrict__ st_in,
                     const unsigned short* __restrict__ rw_u16,
                     float* __restrict__ out, float* __restrict__ final_out, int N) {
  __shared__ alignas(16) unsigned short sT[KD * KD];    // 8 KB: S_n^T swizzled bf16
  __shared__ alignas(16) float obuf[64 * 68];           // 17,408 B: half-tile f32, stride 68

  const int bid = blockIdx.x;
  const int n = bid % N, bh = bid / N;
  const int tid = threadIdx.x;

  // ---- per-thread prefix scan: thread owns (kd = tid>>2, vd = v0..v0+15) ----
  const int kd = tid >> 2, v0 = (tid & 3) * 16;
  const size_t sbase = (size_t)bh * (KD * KD);
  float s[16];
  #pragma unroll
  for (int i = 0; i < 16; i += 4)
    *(f32x4*)&s[i] = *(const f32x4*)&st_in[sbase + kd * KD + v0 + i];

  const float* wseb = wse_ws + (size_t)bh * N * KD + kd;
  const unsigned short* wkvb = wkv_u16 + (size_t)bh * N * (KD * KD) + kd * KD + v0;

  {
    float e_c = 0.f; short8 x0_c = {0}, x1_c = {0};
    if (n > 0) {
      e_c = wseb[0];
      x0_c = *(const short8*)&wkvb[0];
      x1_c = *(const short8*)&wkvb[8];
    }
    for (int j = 0; j < n; ++j) {
      const float e = e_c; const short8 x0 = x0_c, x1 = x1_c;
      if (j + 1 < n) {
        e_c = wseb[(size_t)(j + 1) * KD];
        x0_c = *(const short8*)&wkvb[(size_t)(j + 1) * (KD * KD)];
        x1_c = *(const short8*)&wkvb[(size_t)(j + 1) * (KD * KD) + 8];
      }
      #pragma unroll
      for (int i = 0; i < 8; ++i) {
        s[i]     = s[i]     * e + bf2f((unsigned short)x0[i]);
        s[i + 8] = s[i + 8] * e + bf2f((unsigned short)x1[i]);
      }
    }
  }

  // ---- stage S_n^T into LDS (transpose + swizzle, from registers) ----
  {
    const int g = kd >> 3, k7 = kd & 7;
    #pragma unroll
    for (int i = 0; i < 16; ++i) {
      const int vd = v0 + i;
      sT[vd * KD + (((g ^ (vd & 7)) << 3) | k7)] = f2bf(s[i]);
    }
  }

  // ---- final state: only the n == N-1 blocks do one more step + write ----
  if (n == N - 1) {
    const float e = wseb[(size_t)(N - 1) * KD];
    const short8 x0 = *(const short8*)&wkvb[(size_t)(N - 1) * (KD * KD)];
    const short8 x1 = *(const short8*)&wkvb[(size_t)(N - 1) * (KD * KD) + 8];
    #pragma unroll
    for (int i = 0; i < 8; ++i) {
      s[i]     = s[i]     * e + bf2f((unsigned short)x0[i]);
      s[i + 8] = s[i + 8] * e + bf2f((unsigned short)x1[i]);
    }
    #pragma unroll
    for (int i = 0; i < 16; i += 4)
      *(f32x4*)&final_out[sbase + kd * KD + v0 + i] = *(const f32x4*)&s[i];
  }
  __syncthreads();

  // ---- out += rw @ S_n, epilogue via LDS half-tile for float4 RMW ----
  const int lane = tid & 63, wv = tid >> 6, quad = lane >> 4, l16 = lane & 15;
  const unsigned short* rwg = rw_u16 + ((size_t)bh * N + n) * (TC * KD);
  float* og = out + ((size_t)bh * N + n) * (TC * KD);
  #pragma unroll
  for (int half = 0; half < 2; ++half) {
    const int mt = wv + half * 4;
    const int trow = mt * 16 + l16;
    short8 a0 = *(const short8*)&rwg[trow * KD + quad * 8];
    short8 a1 = *(const short8*)&rwg[trow * KD + 32 + quad * 8];
    const int lr0 = (mt - half * 4) * 16 + quad * 4;   // local row base in obuf
    #pragma unroll
    for (int nn = 0; nn < 4; ++nn) {
      const int vd = nn * 16 + l16;
      short8 b0 = *(const short8*)&sT[vd * KD + ((quad ^ (vd & 7)) << 3)];
      short8 b1 = *(const short8*)&sT[vd * KD + (((4 + quad) ^ (vd & 7)) << 3)];
      f32x4 acc = {0, 0, 0, 0};
      acc = __builtin_amdgcn_mfma_f32_16x16x32_bf16(a0, b0, acc, 0, 0, 0);
      acc = __builtin_amdgcn_mfma_f32_16x16x32_bf16(a1, b1, acc, 0, 0, 0);
      #pragma unroll
      for (int reg = 0; reg < 4; ++reg)
        obuf[(lr0 + reg) * 68 + nn * 16 + l16] = acc[reg];
    }
    __syncthreads();
    // float4 RMW of 64 global rows (16 KB): 4 float4s per thread,
    // 1 KB contiguous per wave per instruction.
    {
      float* ogh = og + half * 64 * KD;
      #pragma unroll
      for (int i = 0; i < 4; ++i) {
        const int f = tid + i * 256;            // float4 index 0..1023
        const int row = f >> 4, c4 = (f & 15) * 4;
        f32x4 l = *(const f32x4*)&obuf[row * 68 + c4];
        f32x4 gv = *(const f32x4*)&ogh[row * KD + c4];
        gv += l;
        *(f32x4*)&ogh[row * KD + c4] = gv;
      }
    }
    __syncthreads();
  }
}

// ---------------------------------------------------------------------------
// Workspace (~24.75 MB): [wkv u16: BH*N*K*K][wse f32: BH*N*K]
//                        [rw u16: BH*T*K][diag u16: BH*N*TC]
// ---------------------------------------------------------------------------
extern "C" void kernel_launch(void* const* d_in, const int* in_sizes, int n_in,
                              void* d_out, int out_size, void* d_ws, size_t ws_size,
                              hipStream_t stream) {
  const float* r = (const float*)d_in[0];
  const float* k = (const float*)d_in[1];
  const float* v = (const float*)d_in[2];
  const float* w = (const float*)d_in[3];
  const float* u = (const float*)d_in[4];
  const float* st0 = (const float*)d_in[5];
  float* out = (float*)d_out;

  const int BH = in_sizes[5] / (KD * KD);  // 64
  const int H = in_sizes[4] / KD;          // 16
  const int T = in_sizes[0] / (BH * KD);   // 2048
  const int N = T / TC;                    // 16

  unsigned short* wkv_u16 = (unsigned short*)d_ws;
  float* wse_ws = (float*)(wkv_u16 + (size_t)BH * N * KD * KD);
  unsigned short* rw_u16 = (unsigned short*)(wse_ws + (size_t)BH * N * KD);
  unsigned short* diag_u16 = rw_u16 + (size_t)BH * T * KD;
  float* final_out = out + (size_t)in_sizes[0];

  rwkv_intra_mfma<<<BH * N, 512, 0, stream>>>(r, k, v, w, u, out, wkv_u16, wse_ws,
                                              rw_u16, diag_u16, H, N);
  rwkv_scan_apply<<<BH * N, 256, 0, stream>>>(wkv_u16, wse_ws, st0, rw_u16,
                                              out, final_out, N);
}

// Round 8
// 194.833 us; speedup vs baseline: 1.0203x; 1.0169x over previous
//
#include <hip/hip_runtime.h>

#define TC 128
#define KD 64
#define WLOG_MIN (-5.2983174f)   // ln(0.005)

typedef __attribute__((ext_vector_type(8))) short short8;
typedef __attribute__((ext_vector_type(4))) short short4_t;
typedef __attribute__((ext_vector_type(4))) float f32x4;

__device__ __forceinline__ unsigned short f2bf(float x) {
  union { float f; unsigned int u; } c; c.f = x;
  unsigned int u = c.u + 0x7fffu + ((c.u >> 16) & 1u);   // RNE
  return (unsigned short)(u >> 16);
}
__device__ __forceinline__ float bf2f(unsigned short x) {
  union { unsigned int u; float f; } c; c.u = ((unsigned int)x) << 16; return c.f;
}

// rd_s/ki_s swizzle: element (t,kd) stored at t*64 + (slot<<3 | kd&7),
// slot = (kd>>3) ^ (t&7) ^ ((t>>3)&7).  b128 granule-q reads use
// slot = q ^ (t&7) ^ ((t>>3)&7).  vT/kiT/sT swizzle: slot = g ^ (row&7).

// ---------------------------------------------------------------------------
// K1 (wkv/wse producer): per-(b,h,chunk), 512 thr. Reads k,v,w only; stages
// kiT/vT (transposed swizzle); 2 wkv tiles per wave; writes wkv bf16 + wse.
// LDS 34,816 B -> 4 blocks/CU = 32 waves/CU (launch_bounds caps VGPR at 64).
// The K1->K2 kernel boundary provides the grid-wide ordering + cache
// visibility that round 7's cooperative grid.sync failed to deliver.
// ---------------------------------------------------------------------------
__global__ __launch_bounds__(512, 8)
void rwkv_wkv(const float* __restrict__ kk_, const float* __restrict__ vv,
              const float* __restrict__ ww,
              unsigned short* __restrict__ wkv_u16, float* __restrict__ wse_ws,
              int N) {
  __shared__ alignas(16) unsigned short vT_s[KD * TC];
  __shared__ alignas(16) unsigned short kiT_s[KD * TC];
  __shared__ alignas(16) float segtot[8 * 64];

  const int bid = blockIdx.x;
  const int n = bid % N, bh = bid / N;
  const size_t base = ((size_t)bh * N + n) * (TC * KD);
  const float *kg = kk_ + base, *vg = vv + base, *wg = ww + base;

  const int tid = threadIdx.x;
  const int lk = tid & 63;    // k-column during staging
  const int wv = tid >> 6;    // wave id = 16-row t-segment

  // ---- pass 1: w clamp + segment totals ----
  float wl[16];
  {
    float c = 0.f;
    #pragma unroll
    for (int tt = 0; tt < 16; ++tt) {
      wl[tt] = fmaxf(wg[(wv * 16 + tt) * KD + lk], WLOG_MIN);
      c += wl[tt];
    }
    segtot[wv * 64 + lk] = c;
  }
  __syncthreads();
  float segofs = 0.f, myoff = 0.f, wsum = 0.f;
  #pragma unroll
  for (int i = 0; i < 8; ++i) {
    const float si = segtot[i * 64 + lk];
    if (i < wv) segofs += si;
    if (i < 4) myoff += si;     // cum at t = Tc/2
    wsum += si;
  }
  const float wsoff_own = __expf(wsum - myoff);
  if (wv == 0) wse_ws[((size_t)bh * N + n) * KD + lk] = __expf(wsum);

  // ---- pass 2: stage ki^T, v^T ----
  {
    float c = segofs;
    short8 vb8, kib8;
    #pragma unroll
    for (int tt = 0; tt < 16; ++tt) {
      const int t = wv * 16 + tt;
      const float kv = kg[t * KD + lk], vvv = vg[t * KD + lk];
      kib8[tt & 7] = (short)f2bf(kv * __expf(myoff - c - wl[tt]));
      vb8[tt & 7] = (short)f2bf(vvv);
      c += wl[tt];
      if ((tt & 7) == 7) {
        const int g = t >> 3;
        *(short8*)&vT_s[lk * TC + ((g ^ (lk & 7)) << 3)] = vb8;
        *(short8*)&kiT_s[lk * TC + ((g ^ (lk & 7)) << 3)] = kib8;
      }
    }
  }
  __syncthreads();

  // ---- wkv = (ki * w_inter)^T @ v -> bf16 (2 of 16 tiles per wave) ----
  {
    const int quad = lk >> 4, l16 = lk & 15;
    const int kt = wv >> 1;             // kd-tile 0..3
    const int nb = (wv & 1) * 2;        // vd-tile base
    f32x4 acc[2] = {{0,0,0,0},{0,0,0,0}};
    const int row = kt * 16 + l16;      // kd row of ki^T
    #pragma unroll
    for (int ks = 0; ks < 4; ++ks) {
      short8 a = *(const short8*)&kiT_s[row * TC + (((ks * 4 + quad) ^ (row & 7)) << 3)];
      #pragma unroll
      for (int nn = 0; nn < 2; ++nn) {
        const int vd = (nb + nn) * 16 + l16;
        short8 b = *(const short8*)&vT_s[vd * TC + (((ks * 4 + quad) ^ (vd & 7)) << 3)];
        acc[nn] = __builtin_amdgcn_mfma_f32_16x16x32_bf16(a, b, acc[nn], 0, 0, 0);
      }
    }
    float wso[4];
    #pragma unroll
    for (int reg = 0; reg < 4; ++reg) wso[reg] = __shfl(wsoff_own, kt * 16 + quad * 4 + reg, 64);
    unsigned short* wkvg = wkv_u16 + ((size_t)bh * N + n) * (KD * KD);
    #pragma unroll
    for (int nn = 0; nn < 2; ++nn)
      #pragma unroll
      for (int reg = 0; reg < 4; ++reg)
        wkvg[(kt * 16 + quad * 4 + reg) * KD + (nb + nn) * 16 + l16] = f2bf(acc[nn][reg] * wso[reg]);
  }
}

// ---------------------------------------------------------------------------
// K2 (main): per-(b,h,chunk), 512 thr. Re-stages r/k/v/w (identical exprs ->
// identical bf16 bits as round 6), computes intra A@v -> regs, scans wkv
// prefix (L3-hot) -> S_n, then out = intra + rw@S_n written ONCE (pure
// write). rw lives in 8 packed VGPRs; diag in LDS. Eliminates vs round 6:
// out RMW (67 MB), rw round-trip (33.6 MB), diag round-trip.
// LDS 59,648 B -> 2 blocks/CU, 16 waves/CU.
// ---------------------------------------------------------------------------
__global__ __launch_bounds__(512, 4)
void rwkv_main(const float* __restrict__ rr, const float* __restrict__ kk_,
               const float* __restrict__ vv, const float* __restrict__ ww,
               const float* __restrict__ uu,
               const unsigned short* __restrict__ wkv_u16,
               const float* __restrict__ wse_ws,
               const float* __restrict__ st_in,
               float* __restrict__ out, float* __restrict__ final_out,
               int H, int N) {
  __shared__ alignas(16) unsigned short rd_s[TC * KD];
  __shared__ alignas(16) unsigned short ki_s[TC * KD];
  __shared__ alignas(16) unsigned short vT_s[KD * TC];
  __shared__ alignas(16) unsigned char su_raw[10240];  // segtot f32[8][64] | Ast u16[8][640]
  __shared__ alignas(16) unsigned short diag_s[TC];
  float* segtot = (float*)su_raw;
  unsigned short* Ast = (unsigned short*)su_raw;

  const int bid = blockIdx.x;
  const int n = bid % N, bh = bid / N, h = bh % H;
  const size_t base = ((size_t)bh * N + n) * (TC * KD);
  const float *rg = rr + base, *kg = kk_ + base, *vg = vv + base, *wg = ww + base;

  const int tid = threadIdx.x;
  const int lk = tid & 63;
  const int wv = tid >> 6;
  const int quad = lk >> 4, l16 = lk & 15;
  const float uk = uu[h * KD + lk];

  // ---- pass 1: w clamp + segment totals ----
  float wl[16];
  {
    float c = 0.f;
    #pragma unroll
    for (int tt = 0; tt < 16; ++tt) {
      wl[tt] = fmaxf(wg[(wv * 16 + tt) * KD + lk], WLOG_MIN);
      c += wl[tt];
    }
    segtot[wv * 64 + lk] = c;
  }
  __syncthreads();
  float segofs = 0.f, myoff = 0.f;
  #pragma unroll
  for (int i = 0; i < 8; ++i) {
    const float si = segtot[i * 64 + lk];
    if (i < wv) segofs += si;
    if (i < 4) myoff += si;     // cum at t = Tc/2
  }
  const float eoff = __expf(myoff);

  // ---- pass 2: staging (rd_s, ki_s, vT_s, rw->regs, diag->LDS) ----
  unsigned int rwp[8];
  {
    float c = segofs;
    short8 vb8;
    float darr[8];
    #pragma unroll
    for (int tt = 0; tt < 16; ++tt) {
      const int t = wv * 16 + tt;
      const float rv = rg[t * KD + lk], kv = kg[t * KD + lk], vvv = vg[t * KD + lk];
      const int slot = (lk >> 3) ^ (t & 7) ^ ((t >> 3) & 7);
      const int nat = t * KD + (slot << 3) + (lk & 7);
      const float e1 = __expf(c - myoff);
      rd_s[nat] = f2bf(rv * e1);
      const unsigned short rwv = f2bf(rv * e1 * eoff);   // r * exp(cum), inter A
      if (tt & 1) rwp[tt >> 1] |= ((unsigned int)rwv) << 16;
      else        rwp[tt >> 1]  = (unsigned int)rwv;
      ki_s[nat] = f2bf(kv * __expf(myoff - c - wl[tt]));
      vb8[tt & 7] = (short)f2bf(vvv);
      darr[tt & 7] = rv * uk * kv;
      c += wl[tt];
      if ((tt & 7) == 7) {
        const int g = t >> 3;
        *(short8*)&vT_s[lk * TC + ((g ^ (lk & 7)) << 3)] = vb8;
        #pragma unroll
        for (int o = 32; o > 0; o >>= 1)
          #pragma unroll
          for (int q = 0; q < 8; ++q) darr[q] += __shfl_xor(darr[q], o, 64);
        if (lk == 0) {
          short8 dpk;
          #pragma unroll
          for (int q = 0; q < 8; ++q) dpk[q] = (short)f2bf(darr[q]);
          *(short8*)&diag_s[g * 8] = dpk;
        }
      }
    }
  }
  __syncthreads();

  // ---- scan prefix (registers; loads issue early, hidden under intra) ----
  const int skd = tid >> 3, sv0 = (tid & 7) * 8;
  const size_t sbase = (size_t)bh * (KD * KD);
  float s[8];
  *(f32x4*)&s[0] = *(const f32x4*)&st_in[sbase + skd * KD + sv0];
  *(f32x4*)&s[4] = *(const f32x4*)&st_in[sbase + skd * KD + sv0 + 4];
  const float* wseb = wse_ws + (size_t)bh * N * KD + skd;
  const unsigned short* wkvb = wkv_u16 + (size_t)bh * N * (KD * KD) + skd * KD + sv0;
  {
    float e_c = 0.f; short8 x_c = {0};
    if (n > 0) {
      e_c = wseb[0];
      x_c = *(const short8*)&wkvb[0];
    }
    for (int j = 0; j < n; ++j) {
      const float e = e_c; const short8 x = x_c;
      if (j + 1 < n) {
        e_c = wseb[(size_t)(j + 1) * KD];
        x_c = *(const short8*)&wkvb[(size_t)(j + 1) * (KD * KD)];
      }
      #pragma unroll
      for (int i = 0; i < 8; ++i) s[i] = s[i] * e + bf2f((unsigned short)x[i]);
    }
  }

  // ---- intra: fused A^T tiles + A@v -> oacc regs (one ib per wave) ----
  f32x4 oacc[4];
  {
    const int ib = wv, i0 = ib * 16, irow = i0 + l16;
    const int rsw = (irow & 7) ^ ((irow >> 3) & 7);
    short8 b0 = *(const short8*)&rd_s[irow * KD + ((quad ^ rsw) << 3)];
    short8 b1 = *(const short8*)&rd_s[irow * KD + (((4 + quad) ^ rsw) << 3)];
    const float diag_i = bf2f(diag_s[irow]);
    #pragma unroll
    for (int nn = 0; nn < 4; ++nn) oacc[nn] = (f32x4){0, 0, 0, 0};
    const int npairs = (ib + 2) >> 1;
    unsigned short* astw = Ast + wv * 640;
    for (int jp = 0; jp < npairs; ++jp) {
      #pragma unroll
      for (int jj = 0; jj < 2; ++jj) {
        const int j = jp * 2 + jj;
        short4_t pk;
        if (j <= ib) {
          const int jrow = j * 16 + l16;
          const int jsw = (jrow & 7) ^ ((jrow >> 3) & 7);
          short8 a0 = *(const short8*)&ki_s[jrow * KD + ((quad ^ jsw) << 3)];
          short8 a1 = *(const short8*)&ki_s[jrow * KD + (((4 + quad) ^ jsw) << 3)];
          f32x4 at = {0, 0, 0, 0};
          at = __builtin_amdgcn_mfma_f32_16x16x32_bf16(a0, b0, at, 0, 0, 0);
          at = __builtin_amdgcn_mfma_f32_16x16x32_bf16(a1, b1, at, 0, 0, 0);
          #pragma unroll
          for (int reg = 0; reg < 4; ++reg) {
            const int je = j * 16 + quad * 4 + reg;
            float val = at[reg];
            if (j == ib) val = (je < irow) ? val : ((je == irow) ? diag_i : 0.f);
            pk[reg] = (short)f2bf(val);
          }
        } else {
          pk = (short4_t)0;  // guard half for even ib
        }
        *(short4_t*)&astw[l16 * 40 + jj * 16 + quad * 4] = pk;
      }
      short8 af = *(const short8*)&astw[l16 * 40 + quad * 8];
      #pragma unroll
      for (int nn = 0; nn < 4; ++nn) {
        const int vd = nn * 16 + l16;
        short8 bv = *(const short8*)&vT_s[vd * TC + (((jp * 4 + quad) ^ (vd & 7)) << 3)];
        oacc[nn] = __builtin_amdgcn_mfma_f32_16x16x32_bf16(af, bv, oacc[nn], 0, 0, 0);
      }
    }
  }
  __syncthreads();   // rd_s/ki_s/vT_s now dead; safe to repurpose

  // ---- sT -> ki_s[0..4096), rw regs -> rd_s (swizzled) ----
  {
    const int g = skd >> 3, k7 = skd & 7;
    #pragma unroll
    for (int i = 0; i < 8; ++i) {
      const int vd = sv0 + i;
      ki_s[vd * KD + (((g ^ (vd & 7)) << 3) | k7)] = f2bf(s[i]);
    }
  }
  #pragma unroll
  for (int tt = 0; tt < 16; ++tt) {
    const int t = wv * 16 + tt;
    const int slot = (lk >> 3) ^ (t & 7) ^ ((t >> 3) & 7);
    const int nat = t * KD + (slot << 3) + (lk & 7);
    const unsigned int pa = rwp[tt >> 1];
    rd_s[nat] = (unsigned short)((tt & 1) ? (pa >> 16) : (pa & 0xffffu));
  }
  if (n == N - 1) {   // final state: one more step then store
    const float e = wseb[(size_t)n * KD];
    const short8 x = *(const short8*)&wkvb[(size_t)n * (KD * KD)];
    #pragma unroll
    for (int i = 0; i < 8; ++i) s[i] = s[i] * e + bf2f((unsigned short)x[i]);
    *(f32x4*)&final_out[sbase + skd * KD + sv0] = *(const f32x4*)&s[0];
    *(f32x4*)&final_out[sbase + skd * KD + sv0 + 4] = *(const f32x4*)&s[4];
  }
  __syncthreads();

  // ---- inter = rw @ S_n; out = intra + inter, single pure-write store ----
  {
    const int ib = wv, trow = ib * 16 + l16;
    const int rsw = (trow & 7) ^ ((trow >> 3) & 7);
    short8 a0 = *(const short8*)&rd_s[trow * KD + ((quad ^ rsw) << 3)];
    short8 a1 = *(const short8*)&rd_s[trow * KD + (((4 + quad) ^ rsw) << 3)];
    float* og = out + base;
    #pragma unroll
    for (int nn = 0; nn < 4; ++nn) {
      const int vd = nn * 16 + l16;
      short8 b0 = *(const short8*)&ki_s[vd * KD + ((quad ^ (vd & 7)) << 3)];
      short8 b1 = *(const short8*)&ki_s[vd * KD + (((4 + quad) ^ (vd & 7)) << 3)];
      f32x4 acc = {0, 0, 0, 0};
      acc = __builtin_amdgcn_mfma_f32_16x16x32_bf16(a0, b0, acc, 0, 0, 0);
      acc = __builtin_amdgcn_mfma_f32_16x16x32_bf16(a1, b1, acc, 0, 0, 0);
      #pragma unroll
      for (int reg = 0; reg < 4; ++reg)
        og[(size_t)(ib * 16 + quad * 4 + reg) * KD + nn * 16 + l16] = oacc[nn][reg] + acc[reg];
    }
  }
}

// ---------------------------------------------------------------------------
// Workspace (~8.9 MB): [wkv u16: BH*N*K*K][wse f32: BH*N*K]
// ---------------------------------------------------------------------------
extern "C" void kernel_launch(void* const* d_in, const int* in_sizes, int n_in,
                              void* d_out, int out_size, void* d_ws, size_t ws_size,
                              hipStream_t stream) {
  const float* r = (const float*)d_in[0];
  const float* k = (const float*)d_in[1];
  const float* v = (const float*)d_in[2];
  const float* w = (const float*)d_in[3];
  const float* u = (const float*)d_in[4];
  const float* st0 = (const float*)d_in[5];
  float* out = (float*)d_out;

  const int BH = in_sizes[5] / (KD * KD);  // 64
  const int H = in_sizes[4] / KD;          // 16
  const int T = in_sizes[0] / (BH * KD);   // 2048
  const int N = T / TC;                    // 16

  unsigned short* wkv_u16 = (unsigned short*)d_ws;
  float* wse_ws = (float*)(wkv_u16 + (size_t)BH * N * KD * KD);
  float* final_out = out + (size_t)in_sizes[0];

  rwkv_wkv<<<BH * N, 512, 0, stream>>>(k, v, w, wkv_u16, wse_ws, N);
  rwkv_main<<<BH * N, 512, 0, stream>>>(r, k, v, w, u, wkv_u16, wse_ws, st0,
                                        out, final_out, H, N);
}